// Round 10
// baseline (256.759 us; speedup 1.0000x reference)
//
#include <hip/hip_runtime.h>
#include <math.h>

#define T_STEPS 168
#define INP     19
#define HID     64
#define ROWS    16
#define NTH     512
#define HSTH    72    // h row stride (f16): 144 B, 16B-aligned
#define XSTH    40    // x row stride (f16): 80 B

typedef _Float16 half8   __attribute__((ext_vector_type(8)));
typedef float    floatx4 __attribute__((ext_vector_type(4)));

// v_exp_f32 IS 2^x. Scale constants are folded into the f16 weights/biases at
// load time (KSIG for sigmoid gates, KTANH for the g gate) so the MFMA output
// is already the exp2 argument.
#define KSIG  (-1.4426950408889634f)   // -log2(e)
#define KTANH ( 2.8853900817779268f)   // 2*log2(e)

// r9 post-mortem: raw inline-asm v_exp_f32 failed at 2 waves/SIMD (opaque asm
// bypasses the hazard recognizer); builtin exp2 validated in r10/r11.
#if defined(__has_builtin)
#  if __has_builtin(__builtin_amdgcn_exp2f)
#    define EXP2(x) __builtin_amdgcn_exp2f(x)
#  else
#    define EXP2(x) exp2f(x)
#  endif
#else
#  define EXP2(x) exp2f(x)
#endif

// r13 = r11 (fused-denominator SCALAR activations, 165us measured, best)
// + ONLY the t-loop unroll-by-2 with compile-time buffer parity.
// r12 post-mortem: unroll+packed-f32 bundled -> 184us regression with
// VALUBusy DOWN (50->37%): issue slots saved, overlap lost. Prime suspect is
// the floatx4 activation form (batched trans phase-serializes trans vs VALU
// within a wave; 2 waves/SIMD can't fill the complementary bubbles). The
// scalar per-rg form keeps 4 independent chains interleaved. This round
// isolates: unroll alone. If it regresses too, unroll is convicted and r11
// is the keeper.
// Buffer discipline at iter t (PAR=t&1, PARX=1-PAR):
//   rd xf[PAR], h1f[PARX], h2f[PAR];  wr xf[PARX], h1f[PAR], h2f[PARX]
__global__ __launch_bounds__(NTH) __attribute__((amdgpu_waves_per_eu(2, 2)))
void lstm2_mfma9_kernel(const float* __restrict__ x,
                        const float* __restrict__ Wih0, const float* __restrict__ Whh0,
                        const float* __restrict__ bih0, const float* __restrict__ bhh0,
                        const float* __restrict__ Wih1, const float* __restrict__ Whh1,
                        const float* __restrict__ bih1, const float* __restrict__ bhh1,
                        const float* __restrict__ Wfc,  const float* __restrict__ bfc,
                        float* __restrict__ out)
{
    __shared__ __align__(16) _Float16 xf [2][ROWS][XSTH];   // cols 19.. stay 0
    __shared__ __align__(16) _Float16 h1f[2][ROWS][HSTH];
    __shared__ __align__(16) _Float16 h2f[2][ROWS][HSTH];
    __shared__ float hout[ROWS][HID];                       // fp32 h2(T-1) for FC

    const int tid  = threadIdx.x;
    const int b0   = blockIdx.x * ROWS;
    const int wv   = tid >> 6;
    const int lane = tid & 63;
    const int quad = lane >> 4;
    const int l16  = lane & 15;
    const int kq   = quad * 8;         // k-offset inside a 32-wide K-tile
    const int lay  = wv >> 2;          // 0: layer1(t), 1: layer2(t-1)
    const int uq   = wv & 3;           // unit quarter
    const int u    = uq * 16 + l16;    // my unit column

    // ---- B-fragments (weights, f16, activation-scale pre-folded) + bias ----
    // B[k][n]: n = lane&15, k = quad*8 + e
    half8 bfr[4][4];
    float bz[4];
#pragma unroll
    for (int gi = 0; gi < 4; ++gi) {
        const float sc = (gi == 2) ? KTANH : KSIG;   // gate order i,f,g,o
        const int gr = gi * 64 + u;
        if (lay == 0) {
            const float* wr = Wih0 + gr * INP;
#pragma unroll
            for (int e = 0; e < 8; ++e) {
                const int k = kq + e;
                bfr[gi][0][e] = (k < INP) ? (_Float16)(wr[k] * sc) : (_Float16)0.0f;
            }
            const float* hr = Whh0 + gr * HID;
#pragma unroll
            for (int e = 0; e < 8; ++e) {
                bfr[gi][1][e] = (_Float16)(hr[kq + e] * sc);
                bfr[gi][2][e] = (_Float16)(hr[32 + kq + e] * sc);
            }
            bfr[gi][3] = bfr[gi][2];   // unused on this path
            bz[gi] = (bih0[gr] + bhh0[gr]) * sc;
        } else {
            const float* ir = Wih1 + gr * HID;
            const float* hr = Whh1 + gr * HID;
#pragma unroll
            for (int e = 0; e < 8; ++e) {
                bfr[gi][0][e] = (_Float16)(ir[kq + e] * sc);
                bfr[gi][1][e] = (_Float16)(ir[32 + kq + e] * sc);
                bfr[gi][2][e] = (_Float16)(hr[kq + e] * sc);
                bfr[gi][3][e] = (_Float16)(hr[32 + kq + e] * sc);
            }
            bz[gi] = (bih1[gr] + bhh1[gr]) * sc;
        }
    }

    // cell state: rows quad*4..+3 of unit u
    float cst[4] = {0.f, 0.f, 0.f, 0.f};

    // ---- x staging constants (threads 0..303 stage one element/iter) ----
    int srr = 0, sii = 0;
    const float* xsrc = nullptr;
    if (tid < ROWS * INP) {
        srr = tid / INP; sii = tid - srr * INP;
        xsrc = x + ((size_t)(b0 + srr) * T_STEPS) * INP + sii;
    }

    // ---- init LDS (both buffers zero; pad cols stay zero forever) ----
    for (int e = tid; e < 2 * ROWS * XSTH; e += NTH) ((_Float16*)xf)[e] = (_Float16)0.f;
    for (int e = tid; e < 2 * ROWS * HSTH; e += NTH) {
        ((_Float16*)h1f)[e] = (_Float16)0.f;
        ((_Float16*)h2f)[e] = (_Float16)0.f;
    }
    __syncthreads();
    float xreg = 0.f;
    if (xsrc) {
        xf[0][srr][sii] = (_Float16)xsrc[0];   // stage x(0) directly
        xreg = xsrc[INP];                      // x(1) held in register
    }
    __syncthreads();

    // ---- one timestep; PAR/PARX are compile-time literals at each call ----
#define STEP(TCUR, PAR, PARX)                                                  \
    do {                                                                       \
        float xnew = 0.f;                                                      \
        if (xsrc) {                                                            \
            const int tn = ((TCUR) + 2 < T_STEPS) ? ((TCUR) + 2)               \
                                                  : (T_STEPS - 1);             \
            xnew = xsrc[(size_t)tn * INP];                                     \
        }                                                                      \
        if (xsrc && ((TCUR) + 1) < T_STEPS)                                    \
            xf[PARX][srr][sii] = (_Float16)xreg;                               \
        const bool act = (lay == 0) ? ((TCUR) < T_STEPS) : ((TCUR) >= 1);      \
        if (act) {                                                             \
            floatx4 acc[4];                                                    \
            _Pragma("unroll")                                                  \
            for (int gi = 0; gi < 4; ++gi)                                     \
                acc[gi] = (floatx4){bz[gi], bz[gi], bz[gi], bz[gi]};           \
            if (lay == 0) {                                                    \
                const half8 ax = *(const half8*)&xf [PAR ][l16][kq];           \
                const half8 a0 = *(const half8*)&h1f[PARX][l16][kq];           \
                const half8 a1 = *(const half8*)&h1f[PARX][l16][32 + kq];      \
                _Pragma("unroll")                                              \
                for (int gi = 0; gi < 4; ++gi) {                               \
                    acc[gi] = __builtin_amdgcn_mfma_f32_16x16x32_f16(          \
                        ax, bfr[gi][0], acc[gi], 0, 0, 0);                     \
                    acc[gi] = __builtin_amdgcn_mfma_f32_16x16x32_f16(          \
                        a0, bfr[gi][1], acc[gi], 0, 0, 0);                     \
                    acc[gi] = __builtin_amdgcn_mfma_f32_16x16x32_f16(          \
                        a1, bfr[gi][2], acc[gi], 0, 0, 0);                     \
                }                                                              \
            } else {                                                           \
                const half8 p0 = *(const half8*)&h1f[PARX][l16][kq];           \
                const half8 p1 = *(const half8*)&h1f[PARX][l16][32 + kq];      \
                const half8 q0 = *(const half8*)&h2f[PAR ][l16][kq];           \
                const half8 q1 = *(const half8*)&h2f[PAR ][l16][32 + kq];      \
                _Pragma("unroll")                                              \
                for (int gi = 0; gi < 4; ++gi) {                               \
                    acc[gi] = __builtin_amdgcn_mfma_f32_16x16x32_f16(          \
                        p0, bfr[gi][0], acc[gi], 0, 0, 0);                     \
                    acc[gi] = __builtin_amdgcn_mfma_f32_16x16x32_f16(          \
                        p1, bfr[gi][1], acc[gi], 0, 0, 0);                     \
                    acc[gi] = __builtin_amdgcn_mfma_f32_16x16x32_f16(          \
                        q0, bfr[gi][2], acc[gi], 0, 0, 0);                     \
                    acc[gi] = __builtin_amdgcn_mfma_f32_16x16x32_f16(          \
                        q1, bfr[gi][3], acc[gi], 0, 0, 0);                     \
                }                                                              \
            }                                                                  \
            /* fused-denominator activations, SCALAR per-rg (r11-validated): */\
            /* 4 independent chains -> trans/VALU interleave across chains */  \
            _Pragma("unroll")                                                  \
            for (int rg = 0; rg < 4; ++rg) {                                   \
                const float Ai = EXP2(acc[0][rg]);     /* e^{-zi} */           \
                const float Af = EXP2(acc[1][rg]);     /* e^{-zf} */           \
                const float Eg = EXP2(acc[2][rg]);     /* e^{2 zg} */          \
                const float Ao = EXP2(acc[3][rg]);     /* e^{-zo} */           \
                const float t1 = 1.0f + Af;                                    \
                const float t2 = 1.0f + Ai;                                    \
                const float t3 = 1.0f + Eg;                                    \
                const float t4 = t2 * t3;                                      \
                const float num = fmaf(Eg - 1.0f, t1, cst[rg] * t4);           \
                const float cn  = num * __builtin_amdgcn_rcpf(t1 * t4);        \
                cst[rg] = cn;                                                  \
                const float cc  = fminf(fmaxf(cn, -30.0f), 30.0f);             \
                const float Ec  = EXP2(KTANH * cc);    /* e^{2 c'} */          \
                const float hv  = (Ec - 1.0f) *                                \
                    __builtin_amdgcn_rcpf((1.0f + Ao) * (Ec + 1.0f));          \
                const int row = quad * 4 + rg;                                 \
                if (lay == 0) {                                                \
                    h1f[PAR][row][u] = (_Float16)hv;            /* h1(t) */    \
                } else {                                                       \
                    h2f[PARX][row][u] = (_Float16)hv;           /* h2(t-1) */  \
                    if ((TCUR) == T_STEPS) hout[row][u] = hv;                  \
                }                                                              \
            }                                                                  \
        }                                                                      \
        xreg = xnew;      /* vm wait lands here, after all compute */          \
        __syncthreads();  /* single barrier per step */                        \
    } while (0)

    // T_STEPS is even: bodies (even,PAR=0) and (odd,PAR=1), tail t=168 PAR=0.
    for (int t = 0; t < T_STEPS; t += 2) {
        STEP(t,     0, 1);
        STEP(t + 1, 1, 0);
    }
    STEP(T_STEPS, 0, 1);
#undef STEP

    // ---- FC epilogue: out[b] = h2(T-1)[b,:] . Wfc + bfc ----
    if (tid < ROWS) {
        float a = bfc[0];
        const float* hr = hout[tid];
#pragma unroll
        for (int k = 0; k < HID; ++k)
            a = fmaf(hr[k], Wfc[k], a);
        out[b0 + tid] = a;
    }
}

extern "C" void kernel_launch(void* const* d_in, const int* in_sizes, int n_in,
                              void* d_out, int out_size, void* d_ws, size_t ws_size,
                              hipStream_t stream) {
    const float* x    = (const float*)d_in[0];
    const float* Wih0 = (const float*)d_in[1];
    const float* Whh0 = (const float*)d_in[2];
    const float* bih0 = (const float*)d_in[3];
    const float* bhh0 = (const float*)d_in[4];
    const float* Wih1 = (const float*)d_in[5];
    const float* Whh1 = (const float*)d_in[6];
    const float* bih1 = (const float*)d_in[7];
    const float* bhh1 = (const float*)d_in[8];
    const float* Wfc  = (const float*)d_in[9];
    const float* bfc  = (const float*)d_in[10];
    float* out = (float*)d_out;

    const int B = in_sizes[0] / (T_STEPS * INP);   // 4096
    const int grid = B / ROWS;                     // 256 workgroups, 1 per CU

    lstm2_mfma9_kernel<<<dim3(grid), dim3(NTH), 0, stream>>>(
        x, Wih0, Whh0, bih0, bhh0, Wih1, Whh1, bih1, bhh1, Wfc, bfc, out);
}

// Round 11
// 233.897 us; speedup vs baseline: 1.0977x; 1.0977x over previous
//
#include <hip/hip_runtime.h>
#include <math.h>

#define T_STEPS 168
#define INP     19
#define HID     64
#define ROWS    16
#define NTH     512
#define HSTH    72    // h row stride (f16): 144 B, 16B-aligned
#define XSTH    40    // x row stride (f16): 80 B

typedef _Float16 half8   __attribute__((ext_vector_type(8)));
typedef float    floatx4 __attribute__((ext_vector_type(4)));

// v_exp_f32 IS 2^x. Scale constants are folded into the f16 weights/biases at
// load time (KSIG for sigmoid gates, KTANH for the g gate) so the MFMA output
// is already the exp2 argument.
#define KSIG  (-1.4426950408889634f)   // -log2(e)
#define KTANH ( 2.8853900817779268f)   // 2*log2(e)

// r9: raw inline-asm v_exp_f32 failed at 2 waves/SIMD (opaque asm bypasses the
// hazard recognizer); builtin exp2 validated in r10/r11.
#if defined(__has_builtin)
#  if __has_builtin(__builtin_amdgcn_exp2f)
#    define EXP2(x) __builtin_amdgcn_exp2f(x)
#  else
#    define EXP2(x) exp2f(x)
#  endif
#else
#  define EXP2(x) exp2f(x)
#endif

// r14 = byte-exact revert to r11, the measured optimum (165.4 us).
// Full neighborhood measured and lost:
//   r8  16-wave duplicated-MFMA:        251 us (+VALU work, convoy unchanged)
//   r12 packed-f32 acts + unroll:       185 us
//   r13 scalar acts + unroll ONLY:      202 us  -> unroll convicted; compact
//       runtime-parity body schedules better than macro-doubled body.
// Load-bearing properties of this form (do not "optimize" away):
//   - SCALAR per-rg fused activations: 4 independent chains let the compiler
//     interleave trans ops of one chain with VALU algebra of another.
//   - runtime (t&1) buffer parity: single compact loop body the scheduler
//     software-pipelines across the barrier.
//   - 8 waves / 2 per SIMD: r8 showed more (correlated) waves regress.
// Fused activation algebra (7 trans/cell):
//   Ai=e^-zi, Af=e^-zf, Eg=e^{2zg}, Ao=e^-zo  (prefolded exp2 args)
//   t1=1+Af t2=1+Ai t3=1+Eg
//   c' = [c*t2*t3 + (Eg-1)*t1] * rcp(t1*t2*t3)       (3 exp + 1 rcp)
//   Ec = 2^{KTANH*clamp(c',+-30)}                     (clamp exact: tanh(30)=1)
//   h  = (Ec-1) * rcp((1+Ao)*(Ec+1))                  (2 exp + 1 rcp)
// Buffer discipline at iter t:  rd xf[t&1], h1f[(t+1)&1], h2f[t&1]
//                               wr xf[(t+1)&1], h1f[t&1], h2f[(t+1)&1]
__global__ __launch_bounds__(NTH) __attribute__((amdgpu_waves_per_eu(2, 2)))
void lstm2_mfma7_kernel(const float* __restrict__ x,
                        const float* __restrict__ Wih0, const float* __restrict__ Whh0,
                        const float* __restrict__ bih0, const float* __restrict__ bhh0,
                        const float* __restrict__ Wih1, const float* __restrict__ Whh1,
                        const float* __restrict__ bih1, const float* __restrict__ bhh1,
                        const float* __restrict__ Wfc,  const float* __restrict__ bfc,
                        float* __restrict__ out)
{
    __shared__ __align__(16) _Float16 xf [2][ROWS][XSTH];   // cols 19.. stay 0
    __shared__ __align__(16) _Float16 h1f[2][ROWS][HSTH];
    __shared__ __align__(16) _Float16 h2f[2][ROWS][HSTH];
    __shared__ float hout[ROWS][HID];                       // fp32 h2(T-1) for FC

    const int tid  = threadIdx.x;
    const int b0   = blockIdx.x * ROWS;
    const int wv   = tid >> 6;
    const int lane = tid & 63;
    const int quad = lane >> 4;
    const int l16  = lane & 15;
    const int kq   = quad * 8;         // k-offset inside a 32-wide K-tile
    const int lay  = wv >> 2;          // 0: layer1(t), 1: layer2(t-1)
    const int uq   = wv & 3;           // unit quarter
    const int u    = uq * 16 + l16;    // my unit column

    // ---- B-fragments (weights, f16, activation-scale pre-folded) + bias ----
    // B[k][n]: n = lane&15, k = quad*8 + e
    half8 bfr[4][4];
    float bz[4];
#pragma unroll
    for (int gi = 0; gi < 4; ++gi) {
        const float sc = (gi == 2) ? KTANH : KSIG;   // gate order i,f,g,o
        const int gr = gi * 64 + u;
        if (lay == 0) {
            const float* wr = Wih0 + gr * INP;
#pragma unroll
            for (int e = 0; e < 8; ++e) {
                const int k = kq + e;
                bfr[gi][0][e] = (k < INP) ? (_Float16)(wr[k] * sc) : (_Float16)0.0f;
            }
            const float* hr = Whh0 + gr * HID;
#pragma unroll
            for (int e = 0; e < 8; ++e) {
                bfr[gi][1][e] = (_Float16)(hr[kq + e] * sc);
                bfr[gi][2][e] = (_Float16)(hr[32 + kq + e] * sc);
            }
            bfr[gi][3] = bfr[gi][2];   // unused on this path
            bz[gi] = (bih0[gr] + bhh0[gr]) * sc;
        } else {
            const float* ir = Wih1 + gr * HID;
            const float* hr = Whh1 + gr * HID;
#pragma unroll
            for (int e = 0; e < 8; ++e) {
                bfr[gi][0][e] = (_Float16)(ir[kq + e] * sc);
                bfr[gi][1][e] = (_Float16)(ir[32 + kq + e] * sc);
                bfr[gi][2][e] = (_Float16)(hr[kq + e] * sc);
                bfr[gi][3][e] = (_Float16)(hr[32 + kq + e] * sc);
            }
            bz[gi] = (bih1[gr] + bhh1[gr]) * sc;
        }
    }

    // cell state: rows quad*4..+3 of unit u
    float cst[4] = {0.f, 0.f, 0.f, 0.f};

    // ---- x staging constants (threads 0..303 stage one element/iter) ----
    int srr = 0, sii = 0;
    const float* xsrc = nullptr;
    if (tid < ROWS * INP) {
        srr = tid / INP; sii = tid - srr * INP;
        xsrc = x + ((size_t)(b0 + srr) * T_STEPS) * INP + sii;
    }

    // ---- init LDS (both buffers zero; pad cols stay zero forever) ----
    for (int e = tid; e < 2 * ROWS * XSTH; e += NTH) ((_Float16*)xf)[e] = (_Float16)0.f;
    for (int e = tid; e < 2 * ROWS * HSTH; e += NTH) {
        ((_Float16*)h1f)[e] = (_Float16)0.f;
        ((_Float16*)h2f)[e] = (_Float16)0.f;
    }
    __syncthreads();
    float xreg = 0.f;
    if (xsrc) {
        xf[0][srr][sii] = (_Float16)xsrc[0];   // stage x(0) directly
        xreg = xsrc[INP];                      // x(1) held in register
    }
    __syncthreads();

    for (int t = 0; t <= T_STEPS; ++t) {
        // ---- issue x(t+2) load FIRST: latency overlaps the whole compute ----
        float xnew = 0.f;
        if (xsrc) {
            const int tn = (t + 2 < T_STEPS) ? (t + 2) : (T_STEPS - 1);
            xnew = xsrc[(size_t)tn * INP];
        }
        // ---- stage x(t+1) from the register loaded last iter (no vm wait) ----
        if (xsrc && (t + 1) < T_STEPS)
            xf[(t + 1) & 1][srr][sii] = (_Float16)xreg;

        const bool act = (lay == 0) ? (t < T_STEPS) : (t >= 1);
        if (act) {
            floatx4 acc[4];
#pragma unroll
            for (int gi = 0; gi < 4; ++gi)
                acc[gi] = (floatx4){bz[gi], bz[gi], bz[gi], bz[gi]};
            if (lay == 0) {
                // A[m=lane&15][k=quad*8+e]
                const half8 ax = *(const half8*)&xf [t & 1][l16][kq];
                const half8 a0 = *(const half8*)&h1f[(t + 1) & 1][l16][kq];
                const half8 a1 = *(const half8*)&h1f[(t + 1) & 1][l16][32 + kq];
#pragma unroll
                for (int gi = 0; gi < 4; ++gi) {
                    acc[gi] = __builtin_amdgcn_mfma_f32_16x16x32_f16(ax, bfr[gi][0], acc[gi], 0, 0, 0);
                    acc[gi] = __builtin_amdgcn_mfma_f32_16x16x32_f16(a0, bfr[gi][1], acc[gi], 0, 0, 0);
                    acc[gi] = __builtin_amdgcn_mfma_f32_16x16x32_f16(a1, bfr[gi][2], acc[gi], 0, 0, 0);
                }
            } else {
                const half8 p0 = *(const half8*)&h1f[(t + 1) & 1][l16][kq];
                const half8 p1 = *(const half8*)&h1f[(t + 1) & 1][l16][32 + kq];
                const half8 q0 = *(const half8*)&h2f[t & 1][l16][kq];
                const half8 q1 = *(const half8*)&h2f[t & 1][l16][32 + kq];
#pragma unroll
                for (int gi = 0; gi < 4; ++gi) {
                    acc[gi] = __builtin_amdgcn_mfma_f32_16x16x32_f16(p0, bfr[gi][0], acc[gi], 0, 0, 0);
                    acc[gi] = __builtin_amdgcn_mfma_f32_16x16x32_f16(p1, bfr[gi][1], acc[gi], 0, 0, 0);
                    acc[gi] = __builtin_amdgcn_mfma_f32_16x16x32_f16(q0, bfr[gi][2], acc[gi], 0, 0, 0);
                    acc[gi] = __builtin_amdgcn_mfma_f32_16x16x32_f16(q1, bfr[gi][3], acc[gi], 0, 0, 0);
                }
            }
            // fused-denominator activations in C-layout:
            // lane owns cells (row=quad*4+rg, u); 7 trans/cell (was 10)
#pragma unroll
            for (int rg = 0; rg < 4; ++rg) {
                const float Ai = EXP2(acc[0][rg]);     // e^{-zi}
                const float Af = EXP2(acc[1][rg]);     // e^{-zf}
                const float Eg = EXP2(acc[2][rg]);     // e^{2 zg}
                const float Ao = EXP2(acc[3][rg]);     // e^{-zo}
                const float t1 = 1.0f + Af;
                const float t2 = 1.0f + Ai;
                const float t3 = 1.0f + Eg;
                const float t4 = t2 * t3;
                const float num = fmaf(Eg - 1.0f, t1, cst[rg] * t4);
                const float cn  = num * __builtin_amdgcn_rcpf(t1 * t4);
                cst[rg] = cn;
                const float cc  = fminf(fmaxf(cn, -30.0f), 30.0f);
                const float Ec  = EXP2(KTANH * cc);    // e^{2 c'}
                const float hv  = (Ec - 1.0f) *
                    __builtin_amdgcn_rcpf((1.0f + Ao) * (Ec + 1.0f));
                const int row = quad * 4 + rg;
                if (lay == 0) {
                    h1f[t & 1][row][u] = (_Float16)hv;              // h1(t)
                } else {
                    h2f[(t + 1) & 1][row][u] = (_Float16)hv;        // h2(t-1)
                    if (t == T_STEPS) hout[row][u] = hv;            // fp32 for FC
                }
            }
        }
        xreg = xnew;       // vm wait lands here, after all compute
        __syncthreads();   // single barrier: iter-t writes visible to iter t+1
    }

    // ---- FC epilogue: out[b] = h2(T-1)[b,:] . Wfc + bfc ----
    if (tid < ROWS) {
        float a = bfc[0];
        const float* hr = hout[tid];
#pragma unroll
        for (int k = 0; k < HID; ++k)
            a = fmaf(hr[k], Wfc[k], a);
        out[b0 + tid] = a;
    }
}

extern "C" void kernel_launch(void* const* d_in, const int* in_sizes, int n_in,
                              void* d_out, int out_size, void* d_ws, size_t ws_size,
                              hipStream_t stream) {
    const float* x    = (const float*)d_in[0];
    const float* Wih0 = (const float*)d_in[1];
    const float* Whh0 = (const float*)d_in[2];
    const float* bih0 = (const float*)d_in[3];
    const float* bhh0 = (const float*)d_in[4];
    const float* Wih1 = (const float*)d_in[5];
    const float* Whh1 = (const float*)d_in[6];
    const float* bih1 = (const float*)d_in[7];
    const float* bhh1 = (const float*)d_in[8];
    const float* Wfc  = (const float*)d_in[9];
    const float* bfc  = (const float*)d_in[10];
    float* out = (float*)d_out;

    const int B = in_sizes[0] / (T_STEPS * INP);   // 4096
    const int grid = B / ROWS;                     // 256 workgroups, 1 per CU

    lstm2_mfma7_kernel<<<dim3(grid), dim3(NTH), 0, stream>>>(
        x, Wih0, Whh0, bih0, bhh0, Wih1, Whh1, bih1, bhh1, Wfc, bfc, out);
}